// Round 1
// baseline (557.295 us; speedup 1.0000x reference)
//
#include <hip/hip_runtime.h>

#define BN 4
#define NN 4096
#define CD 64

typedef __attribute__((ext_vector_type(8))) __bf16 bf16x8;
typedef __attribute__((ext_vector_type(4))) float f32x4;

__device__ __forceinline__ unsigned short f2bf(float x) {
  unsigned int u = __builtin_bit_cast(unsigned int, x);
  u = (u + 0x7fffu + ((u >> 16) & 1u)) >> 16;
  return (unsigned short)u;
}
__device__ __forceinline__ float bf2f(unsigned short s) {
  unsigned int u = ((unsigned int)s) << 16;
  return __builtin_bit_cast(float, u);
}

// ---------------------------------------------------------------------------
// Kernel 1: fold Wz into Wm.
// Wbig[o][c]   = sum_j Wm[o][j] * Wz[j][c]   (c < 128)
// Wbig[o][128+c] = Wm[o][128+c]
// bbig[o]      = bm[o] + sum_j Wm[o][j] * bz[j]
// ---------------------------------------------------------------------------
__global__ void fuse_w_kernel(const float* __restrict__ Wz, const float* __restrict__ bz,
                              const float* __restrict__ Wm, const float* __restrict__ bm,
                              float* __restrict__ Wbig, float* __restrict__ bbig) {
  int idx = blockIdx.x * 256 + threadIdx.x;
  if (idx < 192 * 192) {
    int o = idx / 192, c = idx - o * 192;
    float v;
    if (c < 128) {
      float s = 0.f;
      for (int j = 0; j < 128; ++j) s = fmaf(Wm[o * 192 + j], Wz[j * 128 + c], s);
      v = s;
    } else {
      v = Wm[o * 192 + c];
    }
    Wbig[idx] = v;
  }
  if (idx < 192) {
    float s = bm[idx];
    for (int j = 0; j < 128; ++j) s = fmaf(Wm[idx * 192 + j], bz[j], s);
    bbig[idx] = s;
  }
}

// ---------------------------------------------------------------------------
// Kernel 2: all five 1x1-conv projections.
// Q/Kh/Km stored [B][N][64] bf16 (n-major -> MFMA frags are contiguous 16B).
// Vh/Vm stored [B][64][N] bf16 (c-major -> PV B-frags contiguous 16B).
// ---------------------------------------------------------------------------
__global__ __launch_bounds__(256) void proj_kernel(
    const float* __restrict__ h, const float* __restrict__ m,
    const float* __restrict__ Wq, const float* __restrict__ bq,
    const float* __restrict__ Wk, const float* __restrict__ bk,
    const float* __restrict__ Wk2, const float* __restrict__ bk2,
    const float* __restrict__ Wv, const float* __restrict__ bv,
    const float* __restrict__ Wv2, const float* __restrict__ bv2,
    unsigned short* __restrict__ Q, unsigned short* __restrict__ Kh,
    unsigned short* __restrict__ Km, unsigned short* __restrict__ Vh,
    unsigned short* __restrict__ Vm) {
  __shared__ float hs[64][65];
  __shared__ float ms[64][65];
  int blk = blockIdx.x;            // B * 64
  int ntile = blk & 63, b = blk >> 6;
  int n0 = ntile * 64;
  int t = threadIdx.x;
  int nl = t & 63;
  {
    int c0 = (t >> 6) * 16;
    for (int i = 0; i < 16; ++i) {
      int c = c0 + i;
      hs[c][nl] = h[((size_t)(b * 64) + c) * NN + n0 + nl];
      ms[c][nl] = m[((size_t)(b * 64) + c) * NN + n0 + nl];
    }
  }
  __syncthreads();
  int w = __builtin_amdgcn_readfirstlane(t >> 6);  // wave-uniform o-chunk

  float aQ[16], aKh[16], aKm[16], aVh[16], aVm[16];
#pragma unroll
  for (int i = 0; i < 16; ++i) {
    int o = w * 16 + i;
    aQ[i] = bq[o]; aKh[i] = bk[o]; aKm[i] = bk2[o]; aVh[i] = bv[o]; aVm[i] = bv2[o];
  }
  for (int c = 0; c < 64; ++c) {
    float xh = hs[c][nl];
    float xm = ms[c][nl];
#pragma unroll
    for (int i = 0; i < 16; ++i) {
      int o = w * 16 + i;
      aQ[i]  = fmaf(Wq[o * 64 + c],  xh, aQ[i]);
      aKh[i] = fmaf(Wk[o * 64 + c],  xh, aKh[i]);
      aVh[i] = fmaf(Wv[o * 64 + c],  xh, aVh[i]);
      aKm[i] = fmaf(Wk2[o * 64 + c], xm, aKm[i]);
      aVm[i] = fmaf(Wv2[o * 64 + c], xm, aVm[i]);
    }
  }
  size_t nrow = (size_t)b * NN + n0 + nl;  // row into [B*N]
  // Q/Kh/Km: 16 contiguous bf16 per thread = 2x16B stores
  {
    uint4 p0, p1;
#define PACK16(A, P0, P1)                                                          \
    P0.x = (unsigned)f2bf(A[0]) | ((unsigned)f2bf(A[1]) << 16);                    \
    P0.y = (unsigned)f2bf(A[2]) | ((unsigned)f2bf(A[3]) << 16);                    \
    P0.z = (unsigned)f2bf(A[4]) | ((unsigned)f2bf(A[5]) << 16);                    \
    P0.w = (unsigned)f2bf(A[6]) | ((unsigned)f2bf(A[7]) << 16);                    \
    P1.x = (unsigned)f2bf(A[8]) | ((unsigned)f2bf(A[9]) << 16);                    \
    P1.y = (unsigned)f2bf(A[10]) | ((unsigned)f2bf(A[11]) << 16);                  \
    P1.z = (unsigned)f2bf(A[12]) | ((unsigned)f2bf(A[13]) << 16);                  \
    P1.w = (unsigned)f2bf(A[14]) | ((unsigned)f2bf(A[15]) << 16);
    PACK16(aQ, p0, p1);
    uint4* dst = (uint4*)(Q + nrow * 64 + w * 16);
    dst[0] = p0; dst[1] = p1;
    PACK16(aKh, p0, p1);
    dst = (uint4*)(Kh + nrow * 64 + w * 16);
    dst[0] = p0; dst[1] = p1;
    PACK16(aKm, p0, p1);
    dst = (uint4*)(Km + nrow * 64 + w * 16);
    dst[0] = p0; dst[1] = p1;
#undef PACK16
  }
#pragma unroll
  for (int i = 0; i < 16; ++i) {
    int o = w * 16 + i;
    Vh[((size_t)(b * 64) + o) * NN + n0 + nl] = f2bf(aVh[i]);
    Vm[((size_t)(b * 64) + o) * NN + n0 + nl] = f2bf(aVm[i]);
  }
}

// ---------------------------------------------------------------------------
// Kernel 3: flash attention. One block = 64 query rows of one (b, attn).
// 4 waves x 16 rows. K-tile = 64 cols/iter. Z stored [B][64][N] bf16.
// ---------------------------------------------------------------------------
__global__ __launch_bounds__(256) void flash_kernel(
    const unsigned short* __restrict__ Qg, const unsigned short* __restrict__ Khg,
    const unsigned short* __restrict__ Kmg, const unsigned short* __restrict__ Vhg,
    const unsigned short* __restrict__ Vmg, unsigned short* __restrict__ Zhg,
    unsigned short* __restrict__ Zmg) {
  __shared__ __align__(16) float lds_all[4][16 * 68];  // per-wave scratch
  int blk = blockIdx.x;  // b*128 + attn*64 + qt
  int qt = blk & 63, attn = (blk >> 6) & 1, b = blk >> 7;
  const unsigned short* K = (attn ? Kmg : Khg) + (size_t)b * NN * 64;
  const unsigned short* V = (attn ? Vmg : Vhg) + (size_t)b * 64 * NN;
  unsigned short* Z = (attn ? Zmg : Zhg) + (size_t)b * 64 * NN;
  const unsigned short* Qb = Qg + (size_t)b * NN * 64;

  int t = threadIdx.x;
  int wave = t >> 6, lane = t & 63;
  int col = lane & 15, quad = lane >> 4;
  int row0 = qt * 64 + wave * 16;  // this wave's 16 query rows

  // Q A-frags: A[m=col][k=quad*8+j (+32)], contiguous 16B in [n][d] layout
  bf16x8 aq0, aq1;
  {
    const unsigned short* qp = Qb + (size_t)(row0 + col) * 64 + quad * 8;
    aq0 = *(const bf16x8*)(const void*)qp;
    aq1 = *(const bf16x8*)(const void*)(qp + 32);
  }

  f32x4 O[4];
#pragma unroll
  for (int i = 0; i < 4; ++i) O[i] = f32x4{0.f, 0.f, 0.f, 0.f};
  float m_run[4], l_run[4];
#pragma unroll
  for (int r = 0; r < 4; ++r) { m_run[r] = -1e30f; l_run[r] = 0.f; }

  unsigned short* pbuf = (unsigned short*)lds_all[wave];  // bf16 [16][72]

  for (int kt = 0; kt < 64; ++kt) {
    int k0 = kt * 64;
    // S = Q . K^T  (S[i][j] over 64 keys this tile)
    f32x4 S[4];
#pragma unroll
    for (int nt = 0; nt < 4; ++nt) {
      const unsigned short* kp = K + (size_t)(k0 + nt * 16 + col) * 64 + quad * 8;
      bf16x8 b0 = *(const bf16x8*)(const void*)kp;
      bf16x8 b1 = *(const bf16x8*)(const void*)(kp + 32);
      f32x4 acc = {0.f, 0.f, 0.f, 0.f};
      acc = __builtin_amdgcn_mfma_f32_16x16x32_bf16(aq0, b0, acc, 0, 0, 0);
      acc = __builtin_amdgcn_mfma_f32_16x16x32_bf16(aq1, b1, acc, 0, 0, 0);
      S[nt] = acc;
    }
    // online softmax; C/D layout: row = quad*4+r, col = lane&15 (+16*nt)
    float alpha[4], rs[4];
#pragma unroll
    for (int r = 0; r < 4; ++r) {
      float v = fmaxf(fmaxf(S[0][r], S[1][r]), fmaxf(S[2][r], S[3][r]));
      v = fmaxf(v, __shfl_xor(v, 1));
      v = fmaxf(v, __shfl_xor(v, 2));
      v = fmaxf(v, __shfl_xor(v, 4));
      v = fmaxf(v, __shfl_xor(v, 8));
      float mnew = fmaxf(m_run[r], v);
      alpha[r] = __builtin_exp2f((m_run[r] - mnew) * 1.44269504f);
      m_run[r] = mnew;
      rs[r] = 0.f;
    }
#pragma unroll
    for (int nt = 0; nt < 4; ++nt)
#pragma unroll
      for (int r = 0; r < 4; ++r) {
        float p = __builtin_exp2f((S[nt][r] - m_run[r]) * 1.44269504f);
        S[nt][r] = p;
        rs[r] += p;
      }
#pragma unroll
    for (int r = 0; r < 4; ++r) {
      float v = rs[r];
      v += __shfl_xor(v, 1);
      v += __shfl_xor(v, 2);
      v += __shfl_xor(v, 4);
      v += __shfl_xor(v, 8);
      l_run[r] = l_run[r] * alpha[r] + v;
    }
#pragma unroll
    for (int ct = 0; ct < 4; ++ct)
#pragma unroll
      for (int r = 0; r < 4; ++r) O[ct][r] *= alpha[r];
    // P: C-layout -> LDS -> A-layout (per-wave buffer, no barrier needed)
#pragma unroll
    for (int nt = 0; nt < 4; ++nt)
#pragma unroll
      for (int r = 0; r < 4; ++r)
        pbuf[(quad * 4 + r) * 72 + nt * 16 + col] = f2bf(S[nt][r]);
    bf16x8 ap0 = *(const bf16x8*)(const void*)(pbuf + col * 72 + quad * 8);
    bf16x8 ap1 = *(const bf16x8*)(const void*)(pbuf + col * 72 + 32 + quad * 8);
    // O += P . V^T ; V^T[k][c] = V[c][k] contiguous along k in [c][n] layout
#pragma unroll
    for (int ct = 0; ct < 4; ++ct) {
      const unsigned short* vp = V + (size_t)(ct * 16 + col) * NN + k0 + quad * 8;
      bf16x8 b0 = *(const bf16x8*)(const void*)vp;
      bf16x8 b1 = *(const bf16x8*)(const void*)(vp + 32);
      O[ct] = __builtin_amdgcn_mfma_f32_16x16x32_bf16(ap0, b0, O[ct], 0, 0, 0);
      O[ct] = __builtin_amdgcn_mfma_f32_16x16x32_bf16(ap1, b1, O[ct], 0, 0, 0);
    }
  }
  // finalize: O /= l, transpose via LDS, store Z[c][n] bf16 coalesced
  float invl[4];
#pragma unroll
  for (int r = 0; r < 4; ++r) invl[r] = 1.f / l_run[r];
  float* obuf = lds_all[wave];  // f32 [16 rows][68]
#pragma unroll
  for (int ct = 0; ct < 4; ++ct)
#pragma unroll
    for (int r = 0; r < 4; ++r)
      obuf[(quad * 4 + r) * 68 + ct * 16 + col] = O[ct][r] * invl[r];
  int n_l = lane & 15, cb = lane >> 4;
#pragma unroll
  for (int j = 0; j < 16; ++j) {
    int c = j * 4 + cb;
    Z[(size_t)c * NN + row0 + n_l] = f2bf(obuf[n_l * 68 + c]);
  }
}

// ---------------------------------------------------------------------------
// Kernel 4: combined = Wbig @ [Zh; Zm; h] + bbig, then gating.
// ---------------------------------------------------------------------------
__global__ __launch_bounds__(256) void epilogue_kernel(
    const float* __restrict__ Wbig, const float* __restrict__ bbig,
    const unsigned short* __restrict__ Zh, const unsigned short* __restrict__ Zm,
    const float* __restrict__ hg, const float* __restrict__ mg,
    float* __restrict__ out) {
  __shared__ unsigned short X[192][66];   // bf16
  __shared__ unsigned short Cb[192][66];  // bf16 combined
  int blk = blockIdx.x;  // B * 64
  int ntile = blk & 63, b = blk >> 6;
  int n0 = ntile * 64;
  int t = threadIdx.x;
  int nl = t & 63, w = t >> 6;
#pragma unroll
  for (int i = 0; i < 16; ++i) {
    int c = w + i * 4;
    X[c][nl] = Zh[((size_t)(b * 64) + c) * NN + n0 + nl];
    X[64 + c][nl] = Zm[((size_t)(b * 64) + c) * NN + n0 + nl];
    X[128 + c][nl] = f2bf(hg[((size_t)(b * 64) + c) * NN + n0 + nl]);
  }
  __syncthreads();
  int wu = __builtin_amdgcn_readfirstlane(w);
  const float* wr = Wbig + (size_t)wu * 48 * 192;
  float acc[48];
#pragma unroll
  for (int i = 0; i < 48; ++i) acc[i] = bbig[wu * 48 + i];
  for (int c0 = 0; c0 < 192; c0 += 16) {
    float xv[16];
#pragma unroll
    for (int cc = 0; cc < 16; ++cc) xv[cc] = bf2f(X[c0 + cc][nl]);
#pragma unroll
    for (int i = 0; i < 48; ++i)
#pragma unroll
      for (int cc = 0; cc < 16; ++cc)
        acc[i] = fmaf(wr[i * 192 + c0 + cc], xv[cc], acc[i]);
  }
#pragma unroll
  for (int i = 0; i < 48; ++i) Cb[wu * 48 + i][nl] = f2bf(acc[i]);
  __syncthreads();
#pragma unroll
  for (int i = 0; i < 16; ++i) {
    int o = w * 16 + i;
    float mo = bf2f(Cb[o][nl]);
    float mgt = bf2f(Cb[o + 64][nl]);
    float mi = bf2f(Cb[o + 128][nl]);
    float si = 1.f / (1.f + __expf(-mi));
    float e2 = __expf(2.f * mgt);
    float tg = 1.f - 2.f / (e2 + 1.f);
    float mv = mg[((size_t)(b * 64) + o) * NN + n0 + nl];
    float nm = (1.f - si) * mv + si * tg;
    float so = 1.f / (1.f + __expf(-mo));
    out[((size_t)(b * 64) + o) * NN + n0 + nl] = so * nm;
    out[(size_t)BN * 64 * NN + ((size_t)(b * 64) + o) * NN + n0 + nl] = nm;
  }
}

extern "C" void kernel_launch(void* const* d_in, const int* in_sizes, int n_in,
                              void* d_out, int out_size, void* d_ws, size_t ws_size,
                              hipStream_t stream) {
  const float* h = (const float*)d_in[0];
  const float* m = (const float*)d_in[1];
  const float* Wq = (const float*)d_in[2];
  const float* bq = (const float*)d_in[3];
  const float* Wk = (const float*)d_in[4];
  const float* bk = (const float*)d_in[5];
  const float* Wk2 = (const float*)d_in[6];
  const float* bk2 = (const float*)d_in[7];
  const float* Wv = (const float*)d_in[8];
  const float* bv = (const float*)d_in[9];
  const float* Wv2 = (const float*)d_in[10];
  const float* bv2 = (const float*)d_in[11];
  const float* Wz = (const float*)d_in[12];
  const float* bz = (const float*)d_in[13];
  const float* Wm = (const float*)d_in[14];
  const float* bm = (const float*)d_in[15];
  float* out = (float*)d_out;

  size_t off = 0;
  auto alloc = [&](size_t bytes) {
    void* p = (char*)d_ws + off;
    off += (bytes + 255) & ~(size_t)255;
    return p;
  };
  const size_t bn64 = (size_t)BN * NN * 64;  // elements per projection tensor
  unsigned short* Q  = (unsigned short*)alloc(bn64 * 2);
  unsigned short* Kh = (unsigned short*)alloc(bn64 * 2);
  unsigned short* Km = (unsigned short*)alloc(bn64 * 2);
  unsigned short* Vh = (unsigned short*)alloc(bn64 * 2);
  unsigned short* Vm = (unsigned short*)alloc(bn64 * 2);
  unsigned short* Zh = (unsigned short*)alloc(bn64 * 2);
  unsigned short* Zm = (unsigned short*)alloc(bn64 * 2);
  float* Wbig = (float*)alloc(192 * 192 * 4);
  float* bbig = (float*)alloc(192 * 4);
  (void)ws_size; (void)in_sizes; (void)n_in; (void)out_size;

  fuse_w_kernel<<<144, 256, 0, stream>>>(Wz, bz, Wm, bm, Wbig, bbig);
  proj_kernel<<<BN * 64, 256, 0, stream>>>(h, m, Wq, bq, Wk, bk, Wk2, bk2, Wv, bv,
                                           Wv2, bv2, Q, Kh, Km, Vh, Vm);
  flash_kernel<<<BN * 2 * 64, 256, 0, stream>>>(Q, Kh, Km, Vh, Vm, Zh, Zm);
  epilogue_kernel<<<BN * 64, 256, 0, stream>>>(Wbig, bbig, Zh, Zm, h, m, out);
}

// Round 3
// 493.337 us; speedup vs baseline: 1.1296x; 1.1296x over previous
//
#include <hip/hip_runtime.h>

#define BN 4
#define NN 4096
#define SPLITK 2
#define LOG2E 1.44269504f

typedef __attribute__((ext_vector_type(8))) __bf16 bf16x8;
typedef __attribute__((ext_vector_type(4))) short s16x4;
typedef __attribute__((ext_vector_type(4))) float f32x4;
typedef unsigned short u16;

__device__ __forceinline__ u16 f2bf(float x) {  // manual RNE
  unsigned int u = __builtin_bit_cast(unsigned int, x);
  u = (u + 0x7fffu + ((u >> 16) & 1u)) >> 16;
  return (u16)u;
}
__device__ __forceinline__ u16 f2bfs(float x) {  // hw cvt path
  __bf16 b = (__bf16)x;
  return __builtin_bit_cast(u16, b);
}
__device__ __forceinline__ float bf2f(u16 s) {
  unsigned int u = ((unsigned int)s) << 16;
  return __builtin_bit_cast(float, u);
}

// v_mfma_f32_16x16x16_bf16 (gfx950 ISA §10; A/B = 4 bf16 in 2 VGPRs).
// Guard: amdgcn builtins are undeclared in the HOST pass (that's what broke R2);
// host never executes device code, so a trivial stub is fine there.
__device__ __forceinline__ f32x4 mfma16(s16x4 a, s16x4 b, f32x4 c) {
#if defined(__HIP_DEVICE_COMPILE__)
  return __builtin_amdgcn_mfma_f32_16x16x16bf16_1k(a, b, c, 0, 0, 0);
#else
  return c;
#endif
}

// ---------------------------------------------------------------------------
// Kernel 1: fold Wz into Wm; emit bf16 Wbig + fp32 bbig.
// ---------------------------------------------------------------------------
__global__ void fuse_w_kernel(const float* __restrict__ Wz, const float* __restrict__ bz,
                              const float* __restrict__ Wm, const float* __restrict__ bm,
                              u16* __restrict__ Wbig, float* __restrict__ bbig) {
  int idx = blockIdx.x * 256 + threadIdx.x;
  if (idx < 192 * 192) {
    int o = idx / 192, c = idx - o * 192;
    float v;
    if (c < 128) {
      float s = 0.f;
      for (int j = 0; j < 128; ++j) s = fmaf(Wm[o * 192 + j], Wz[j * 128 + c], s);
      v = s;
    } else {
      v = Wm[o * 192 + c];
    }
    Wbig[idx] = f2bf(v);
  }
  if (idx < 192) {
    float s = bm[idx];
    for (int j = 0; j < 128; ++j) s = fmaf(Wm[idx * 192 + j], bz[j], s);
    bbig[idx] = s;
  }
}

// ---------------------------------------------------------------------------
// Kernel 2: all five 1x1-conv projections (+ hT emit).
// Q (pre-scaled by log2e) / Kh / Km / hT stored [B][N][64] bf16.
// Vh/Vm stored [B][64][N] bf16.
// ---------------------------------------------------------------------------
__global__ __launch_bounds__(256) void proj_kernel(
    const float* __restrict__ h, const float* __restrict__ m,
    const float* __restrict__ Wq, const float* __restrict__ bq,
    const float* __restrict__ Wk, const float* __restrict__ bk,
    const float* __restrict__ Wk2, const float* __restrict__ bk2,
    const float* __restrict__ Wv, const float* __restrict__ bv,
    const float* __restrict__ Wv2, const float* __restrict__ bv2,
    u16* __restrict__ Q, u16* __restrict__ Kh, u16* __restrict__ Km,
    u16* __restrict__ Vh, u16* __restrict__ Vm, u16* __restrict__ hT) {
  __shared__ float hs[64][65];
  __shared__ float ms[64][65];
  int blk = blockIdx.x;  // B * 64
  int ntile = blk & 63, b = blk >> 6;
  int n0 = ntile * 64;
  int t = threadIdx.x;
  int nl = t & 63;
  {
    int c0 = (t >> 6) * 16;
    for (int i = 0; i < 16; ++i) {
      int c = c0 + i;
      hs[c][nl] = h[((size_t)(b * 64) + c) * NN + n0 + nl];
      ms[c][nl] = m[((size_t)(b * 64) + c) * NN + n0 + nl];
    }
  }
  __syncthreads();
  int w = __builtin_amdgcn_readfirstlane(t >> 6);

  float aQ[16], aKh[16], aKm[16], aVh[16], aVm[16];
#pragma unroll
  for (int i = 0; i < 16; ++i) {
    int o = w * 16 + i;
    aQ[i] = bq[o]; aKh[i] = bk[o]; aKm[i] = bk2[o]; aVh[i] = bv[o]; aVm[i] = bv2[o];
  }
  for (int c = 0; c < 64; ++c) {
    float xh = hs[c][nl];
    float xm = ms[c][nl];
#pragma unroll
    for (int i = 0; i < 16; ++i) {
      int o = w * 16 + i;
      aQ[i]  = fmaf(Wq[o * 64 + c],  xh, aQ[i]);
      aKh[i] = fmaf(Wk[o * 64 + c],  xh, aKh[i]);
      aVh[i] = fmaf(Wv[o * 64 + c],  xh, aVh[i]);
      aKm[i] = fmaf(Wk2[o * 64 + c], xm, aKm[i]);
      aVm[i] = fmaf(Wv2[o * 64 + c], xm, aVm[i]);
    }
  }
#pragma unroll
  for (int i = 0; i < 16; ++i) aQ[i] *= LOG2E;  // fold softmax log2e into Q
  size_t nrow = (size_t)b * NN + n0 + nl;
  {
    uint4 p0, p1;
#define PACK16(A, P0, P1)                                                          \
    P0.x = (unsigned)f2bf(A[0]) | ((unsigned)f2bf(A[1]) << 16);                    \
    P0.y = (unsigned)f2bf(A[2]) | ((unsigned)f2bf(A[3]) << 16);                    \
    P0.z = (unsigned)f2bf(A[4]) | ((unsigned)f2bf(A[5]) << 16);                    \
    P0.w = (unsigned)f2bf(A[6]) | ((unsigned)f2bf(A[7]) << 16);                    \
    P1.x = (unsigned)f2bf(A[8]) | ((unsigned)f2bf(A[9]) << 16);                    \
    P1.y = (unsigned)f2bf(A[10]) | ((unsigned)f2bf(A[11]) << 16);                  \
    P1.z = (unsigned)f2bf(A[12]) | ((unsigned)f2bf(A[13]) << 16);                  \
    P1.w = (unsigned)f2bf(A[14]) | ((unsigned)f2bf(A[15]) << 16);
    PACK16(aQ, p0, p1);
    uint4* dst = (uint4*)(Q + nrow * 64 + w * 16);
    dst[0] = p0; dst[1] = p1;
    PACK16(aKh, p0, p1);
    dst = (uint4*)(Kh + nrow * 64 + w * 16);
    dst[0] = p0; dst[1] = p1;
    PACK16(aKm, p0, p1);
    dst = (uint4*)(Km + nrow * 64 + w * 16);
    dst[0] = p0; dst[1] = p1;
    float tv[16];
#pragma unroll
    for (int i = 0; i < 16; ++i) tv[i] = hs[w * 16 + i][nl];
    PACK16(tv, p0, p1);
    dst = (uint4*)(hT + nrow * 64 + w * 16);
    dst[0] = p0; dst[1] = p1;
#undef PACK16
  }
#pragma unroll
  for (int i = 0; i < 16; ++i) {
    int o = w * 16 + i;
    Vh[((size_t)(b * 64) + o) * NN + n0 + nl] = f2bf(aVh[i]);
    Vm[((size_t)(b * 64) + o) * NN + n0 + nl] = f2bf(aVm[i]);
  }
}

// ---------------------------------------------------------------------------
// Kernel 3: transposed flash, split-K. No LDS at all.
// St = K.Q^T (A=K-frag, B=Q-frag, 16x16x32): lane holds St[key=quad*4+r+16nt][q=col].
// exp() results are directly the A-operand of 16x16x16 PV MFMAs (k=quad*4+r).
// O[q=quad*4+r][c=ct*16+col] partials -> Opart bf16; m/l fp32 per q.
// ---------------------------------------------------------------------------
__global__ __launch_bounds__(256) void flash2_kernel(
    const u16* __restrict__ Qg, const u16* __restrict__ Khg,
    const u16* __restrict__ Kmg, const u16* __restrict__ Vhg,
    const u16* __restrict__ Vmg, u16* __restrict__ Opart,
    float* __restrict__ Mpart, float* __restrict__ Lpart) {
  int blk = blockIdx.x;  // split*512 + b*128 + attn*64 + qt
  int qt = blk & 63, attn = (blk >> 6) & 1, b = (blk >> 7) & 3, split = blk >> 9;
  const u16* K = (attn ? Kmg : Khg) + (size_t)b * NN * 64;
  const u16* V = (attn ? Vmg : Vhg) + (size_t)b * 64 * NN;
  int t = threadIdx.x, wave = t >> 6, lane = t & 63, col = lane & 15, quad = lane >> 4;
  int row0 = qt * 64 + wave * 16;

  const u16* qp = Qg + (size_t)b * NN * 64 + (size_t)(row0 + col) * 64 + quad * 8;
  bf16x8 bq0 = *(const bf16x8*)(const void*)qp;
  bf16x8 bq1 = *(const bf16x8*)(const void*)(qp + 32);

  f32x4 O[4];
#pragma unroll
  for (int i = 0; i < 4; ++i) O[i] = f32x4{0.f, 0.f, 0.f, 0.f};
  float m_run = -1e30f, l_run = 0.f;
  int sp8 = split * 8 + b * 2 + attn;

  for (int kt = 0; kt < NN / SPLITK / 64; ++kt) {
    int k0 = split * (NN / SPLITK) + kt * 64;
    // St = K . Q^T  (scores already in log2 units: Q pre-scaled by log2e)
    f32x4 St[4];
#pragma unroll
    for (int nt = 0; nt < 4; ++nt) {
      const u16* kp = K + (size_t)(k0 + nt * 16 + col) * 64 + quad * 8;
      bf16x8 a0 = *(const bf16x8*)(const void*)kp;
      bf16x8 a1 = *(const bf16x8*)(const void*)(kp + 32);
      f32x4 acc = {0.f, 0.f, 0.f, 0.f};
      acc = __builtin_amdgcn_mfma_f32_16x16x32_bf16(a0, bq0, acc, 0, 0, 0);
      acc = __builtin_amdgcn_mfma_f32_16x16x32_bf16(a1, bq1, acc, 0, 0, 0);
      St[nt] = acc;
    }
    // per-query (q=col) max: per-lane over 16 regs, then across quads
    float mx;
    {
      float m0 = fmaxf(fmaxf(St[0][0], St[1][0]), fmaxf(St[2][0], St[3][0]));
      float m1 = fmaxf(fmaxf(St[0][1], St[1][1]), fmaxf(St[2][1], St[3][1]));
      float m2 = fmaxf(fmaxf(St[0][2], St[1][2]), fmaxf(St[2][2], St[3][2]));
      float m3 = fmaxf(fmaxf(St[0][3], St[1][3]), fmaxf(St[2][3], St[3][3]));
      mx = fmaxf(fmaxf(m0, m1), fmaxf(m2, m3));
      mx = fmaxf(mx, __shfl_xor(mx, 16));
      mx = fmaxf(mx, __shfl_xor(mx, 32));
    }
    float mnew = fmaxf(m_run, mx);
    float alpha = __builtin_exp2f(m_run - mnew);
    m_run = mnew;
    // exp + row-sum + pack A-frags for PV
    float rs = 0.f;
    s16x4 pfrag[4];
#pragma unroll
    for (int nt = 0; nt < 4; ++nt) {
      f32x4 p;
#pragma unroll
      for (int r = 0; r < 4; ++r) p[r] = __builtin_exp2f(St[nt][r] - m_run);
      rs += (p[0] + p[1]) + (p[2] + p[3]);
      s16x4 pf;
#pragma unroll
      for (int r = 0; r < 4; ++r) pf[r] = (short)f2bfs(p[r]);
      pfrag[nt] = pf;
    }
    rs += __shfl_xor(rs, 16);
    rs += __shfl_xor(rs, 32);
    l_run = l_run * alpha + rs;
    // redistribute alpha to O rows (q = quad*4+r): lane l<16 has col=l
    float al[4];
#pragma unroll
    for (int r = 0; r < 4; ++r) al[r] = __shfl(alpha, (quad << 2) + r, 64);
#pragma unroll
    for (int ct = 0; ct < 4; ++ct)
#pragma unroll
      for (int r = 0; r < 4; ++r) O[ct][r] *= al[r];
    // O += P . V^T via 16x16x16 MFMAs (P in registers!)
#pragma unroll
    for (int nt = 0; nt < 4; ++nt) {
#pragma unroll
      for (int ct = 0; ct < 4; ++ct) {
        const u16* vp = V + (size_t)(ct * 16 + col) * NN + k0 + nt * 16 + quad * 4;
        s16x4 vf = *(const s16x4*)(const void*)vp;
        O[ct] = mfma16(pfrag[nt], vf, O[ct]);
      }
    }
  }
  // store partials (no /l here; merge kernel combines splits)
#pragma unroll
  for (int ct = 0; ct < 4; ++ct)
#pragma unroll
    for (int r = 0; r < 4; ++r) {
      size_t q = (size_t)row0 + quad * 4 + r;
      Opart[((size_t)sp8 * NN + q) * 64 + ct * 16 + col] = f2bfs(O[ct][r]);
    }
  if (lane < 16) {
    size_t idx = (size_t)sp8 * NN + row0 + lane;
    Mpart[idx] = m_run;
    Lpart[idx] = l_run;
  }
}

// ---------------------------------------------------------------------------
// Kernel 4: merge SPLITK partials -> Zh/Zm in [B][N][64] bf16 layout.
// ---------------------------------------------------------------------------
__global__ __launch_bounds__(256) void merge_kernel(
    const u16* __restrict__ Opart, const float* __restrict__ Mpart,
    const float* __restrict__ Lpart, u16* __restrict__ Zh, u16* __restrict__ Zm) {
  int g = blockIdx.x * 256 + threadIdx.x;  // B*2*NN*64 total
  int c = g & 63;
  int q = (g >> 6) & (NN - 1);
  int b2 = g >> 18;  // 0..7 = b*2+attn
  size_t i0 = (size_t)b2 * NN + q;
  size_t i1 = (size_t)(8 + b2) * NN + q;
  float m0 = Mpart[i0], m1 = Mpart[i1];
  float l0 = Lpart[i0], l1 = Lpart[i1];
  float M = fmaxf(m0, m1);
  float a0 = __builtin_exp2f(m0 - M), a1 = __builtin_exp2f(m1 - M);
  float L = a0 * l0 + a1 * l1;
  float o = a0 * bf2f(Opart[i0 * 64 + c]) + a1 * bf2f(Opart[i1 * 64 + c]);
  float z = o / L;
  u16* Z = (b2 & 1) ? Zm : Zh;
  int b = b2 >> 1;
  Z[((size_t)b * NN + q) * 64 + c] = f2bfs(z);
}

// ---------------------------------------------------------------------------
// Kernel 5: MFMA epilogue. combined = Wbig @ [Zh;Zm;h] + bbig, then gating.
// B-frags are contiguous 16B loads from [n][64] bf16 arrays -> no LDS.
// Wave w owns output tiles {w, w+4, w+8} so (mo, mg, mi) land in one lane.
// ---------------------------------------------------------------------------
__global__ __launch_bounds__(256) void epi2_kernel(
    const u16* __restrict__ Wb, const float* __restrict__ bb,
    const u16* __restrict__ Zh, const u16* __restrict__ Zm,
    const u16* __restrict__ hT, const float* __restrict__ mglob,
    float* __restrict__ out) {
  int blk = blockIdx.x;  // B*NN/16 = 1024
  int ng = blk * 16;
  int b = ng >> 12;
  int t = threadIdx.x, wave = t >> 6, lane = t & 63, col = lane & 15, quad = lane >> 4;
  size_t nrow = ((size_t)ng + col) * 64;
  bf16x8 bfr[6];
  bfr[0] = *(const bf16x8*)(const void*)(Zh + nrow + quad * 8);
  bfr[1] = *(const bf16x8*)(const void*)(Zh + nrow + 32 + quad * 8);
  bfr[2] = *(const bf16x8*)(const void*)(Zm + nrow + quad * 8);
  bfr[3] = *(const bf16x8*)(const void*)(Zm + nrow + 32 + quad * 8);
  bfr[4] = *(const bf16x8*)(const void*)(hT + nrow + quad * 8);
  bfr[5] = *(const bf16x8*)(const void*)(hT + nrow + 32 + quad * 8);
  f32x4 acc[3];
#pragma unroll
  for (int j = 0; j < 3; ++j) {
    int mt = wave + j * 4;
#pragma unroll
    for (int r = 0; r < 4; ++r) acc[j][r] = bb[mt * 16 + quad * 4 + r];
  }
#pragma unroll
  for (int ks = 0; ks < 6; ++ks) {
#pragma unroll
    for (int j = 0; j < 3; ++j) {
      int mt = wave + j * 4;
      bf16x8 af = *(const bf16x8*)(const void*)(Wb + (size_t)(mt * 16 + col) * 192 + ks * 32 + quad * 8);
      acc[j] = __builtin_amdgcn_mfma_f32_16x16x32_bf16(af, bfr[ks], acc[j], 0, 0, 0);
    }
  }
  int nloc = (ng & (NN - 1)) + col;
#pragma unroll
  for (int r = 0; r < 4; ++r) {
    int o = wave * 16 + quad * 4 + r;
    float mo = acc[0][r], mgt = acc[1][r], mi = acc[2][r];
    float si = 1.f / (1.f + __builtin_exp2f(-mi * LOG2E));
    float tg = 1.f - 2.f / (__builtin_exp2f(2.f * LOG2E * mgt) + 1.f);
    float mv = mglob[(size_t)(b * 64 + o) * NN + nloc];
    float nm = (1.f - si) * mv + si * tg;
    float nh = nm / (1.f + __builtin_exp2f(-mo * LOG2E));
    out[(size_t)(b * 64 + o) * NN + nloc] = nh;
    out[(size_t)BN * 64 * NN + (size_t)(b * 64 + o) * NN + nloc] = nm;
  }
}

extern "C" void kernel_launch(void* const* d_in, const int* in_sizes, int n_in,
                              void* d_out, int out_size, void* d_ws, size_t ws_size,
                              hipStream_t stream) {
  const float* h = (const float*)d_in[0];
  const float* m = (const float*)d_in[1];
  const float* Wq = (const float*)d_in[2];
  const float* bq = (const float*)d_in[3];
  const float* Wk = (const float*)d_in[4];
  const float* bk = (const float*)d_in[5];
  const float* Wk2 = (const float*)d_in[6];
  const float* bk2 = (const float*)d_in[7];
  const float* Wv = (const float*)d_in[8];
  const float* bv = (const float*)d_in[9];
  const float* Wv2 = (const float*)d_in[10];
  const float* bv2 = (const float*)d_in[11];
  const float* Wz = (const float*)d_in[12];
  const float* bz = (const float*)d_in[13];
  const float* Wm = (const float*)d_in[14];
  const float* bm = (const float*)d_in[15];
  float* out = (float*)d_out;

  size_t off = 0;
  auto alloc = [&](size_t bytes) {
    void* p = (char*)d_ws + off;
    off += (bytes + 255) & ~(size_t)255;
    return p;
  };
  const size_t bn64 = (size_t)BN * NN * 64;
  u16* Q  = (u16*)alloc(bn64 * 2);
  u16* Kh = (u16*)alloc(bn64 * 2);
  u16* Km = (u16*)alloc(bn64 * 2);
  u16* Vh = (u16*)alloc(bn64 * 2);
  u16* Vm = (u16*)alloc(bn64 * 2);
  u16* hT = (u16*)alloc(bn64 * 2);
  u16* Zh = (u16*)alloc(bn64 * 2);
  u16* Zm = (u16*)alloc(bn64 * 2);
  u16* Opart = (u16*)alloc((size_t)SPLITK * 8 * NN * 64 * 2);
  float* Mpart = (float*)alloc((size_t)SPLITK * 8 * NN * 4);
  float* Lpart = (float*)alloc((size_t)SPLITK * 8 * NN * 4);
  u16* Wbigbf = (u16*)alloc(192 * 192 * 2);
  float* bbig = (float*)alloc(192 * 4);
  (void)ws_size; (void)in_sizes; (void)n_in; (void)out_size;

  fuse_w_kernel<<<144, 256, 0, stream>>>(Wz, bz, Wm, bm, Wbigbf, bbig);
  proj_kernel<<<BN * 64, 256, 0, stream>>>(h, m, Wq, bq, Wk, bk, Wk2, bk2, Wv, bv,
                                           Wv2, bv2, Q, Kh, Km, Vh, Vm, hT);
  flash2_kernel<<<SPLITK * BN * 2 * 64, 256, 0, stream>>>(Q, Kh, Km, Vh, Vm,
                                                          Opart, Mpart, Lpart);
  merge_kernel<<<(BN * 2 * NN * 64) / 256, 256, 0, stream>>>(Opart, Mpart, Lpart, Zh, Zm);
  epi2_kernel<<<(BN * NN) / 16, 256, 0, stream>>>(Wbigbf, bbig, Zh, Zm, hT, m, out);
}